// Round 2
// baseline (694.465 us; speedup 1.0000x reference)
//
#include <hip/hip_runtime.h>
#include <hip/hip_bf16.h>
#include <stdint.h>

// Pairwise squared L2: out[i][j] = max(x2[i] + y2[j] - 2*dot(x_i,y_j), 0)
// dot computed via bf16x3 split (hi/lo) single GEMM with K = 3*D = 2304.

#define M_DIM 8192
#define N_DIM 8192
#define D_DIM 768
#define K_DIM (3 * D_DIM)   // 2304
#define BM 128
#define BN 128
#define BK 32

typedef __bf16 bf16x8 __attribute__((ext_vector_type(8)));
typedef float f32x4 __attribute__((ext_vector_type(4)));

#define GLOAD_LDS16(g, l) \
  __builtin_amdgcn_global_load_lds((const __attribute__((address_space(1))) void*)(g), \
                                   (__attribute__((address_space(3))) void*)(l), 16, 0, 0)

// Pack one fp32 row into bf16 [seg, seg, seg] layout:
// hi written at off_hi0 and off_hi1, lo at off_lo. Also writes row sum-of-squares.
__global__ __launch_bounds__(256) void pack_kernel(
    const float* __restrict__ in, __hip_bfloat16* __restrict__ pk,
    float* __restrict__ nrm, int off_hi0, int off_hi1, int off_lo)
{
  int row = blockIdx.x;
  int tid = threadIdx.x;
  const float* r = in + (size_t)row * D_DIM;
  __hip_bfloat16* p = pk + (size_t)row * K_DIM;
  float ss = 0.f;
  for (int d = tid; d < D_DIM; d += 256) {
    float v = r[d];
    ss += v * v;
    __hip_bfloat16 hi = __float2bfloat16(v);
    float hv = __bfloat162float(hi);
    __hip_bfloat16 lo = __float2bfloat16(v - hv);
    p[off_hi0 + d] = hi;
    p[off_hi1 + d] = hi;
    p[off_lo  + d] = lo;
  }
  // block reduction of sum-of-squares
  #pragma unroll
  for (int o = 32; o > 0; o >>= 1) ss += __shfl_down(ss, o, 64);
  __shared__ float warp_s[4];
  int lane = tid & 63, wid = tid >> 6;
  if (lane == 0) warp_s[wid] = ss;
  __syncthreads();
  if (tid == 0) nrm[row] = warp_s[0] + warp_s[1] + warp_s[2] + warp_s[3];
}

// m97-structure GEMM (128x128 tile, BK=32, 4 waves, 16x16x32 bf16 MFMA,
// global_load_lds width-16 staging, fused distance epilogue).
__global__ __launch_bounds__(256, 2) void dist_gemm(
    const __hip_bfloat16* __restrict__ A, const __hip_bfloat16* __restrict__ Bp,
    const float* __restrict__ x2, const float* __restrict__ y2,
    float* __restrict__ out)
{
  __shared__ __attribute__((aligned(16))) __hip_bfloat16 As[BM * BK]; // 8 KB
  __shared__ __attribute__((aligned(16))) __hip_bfloat16 Bs[BN * BK]; // 8 KB

  int bid = blockIdx.x;
  // XCD-aware bijective swizzle: 4096 blocks, 4096 % 8 == 0
  int swz = (bid & 7) * 512 + (bid >> 3);
  int tileRow = swz >> 6;        // 64 tiles per dim
  int tileCol = swz & 63;
  int rowBase = tileRow * BM;
  int colBase = tileCol * BN;

  int tid  = threadIdx.x;
  int lane = tid & 63;
  int wid  = tid >> 6;           // 0..3
  int wr = wid >> 1, wc = wid & 1;

  f32x4 acc[4][4];
  #pragma unroll
  for (int m = 0; m < 4; ++m)
    #pragma unroll
    for (int n = 0; n < 4; ++n)
      acc[m][n] = (f32x4){0.f, 0.f, 0.f, 0.f};

  int reg0 = wid * 2;            // two 1024B LDS regions per wave per tile
  int kc = (lane >> 4) * 8;      // k-chunk within fragment
  int rl = lane & 15;

  for (int kt = 0; kt < K_DIM / BK; ++kt) {
    int k0 = kt * BK;
    #pragma unroll
    for (int i = 0; i < 2; ++i) {
      int c = (reg0 + i) * 64 + lane;      // 16B-chunk index within tile
      int arow = c >> 2;                   // 4 chunks per 64B row
      int cc = (c & 3) * 8;                // element offset within row
      const __hip_bfloat16* ga = A  + (size_t)(rowBase + arow) * K_DIM + k0 + cc;
      const __hip_bfloat16* gb = Bp + (size_t)(colBase + arow) * K_DIM + k0 + cc;
      GLOAD_LDS16(ga, (char*)As + (reg0 + i) * 1024);
      GLOAD_LDS16(gb, (char*)Bs + (reg0 + i) * 1024);
    }
    __syncthreads();

    bf16x8 af[4], bfr[4];
    #pragma unroll
    for (int m = 0; m < 4; ++m)
      af[m] = *(const bf16x8*)&As[(wr * 64 + m * 16 + rl) * BK + kc];
    #pragma unroll
    for (int n = 0; n < 4; ++n)
      bfr[n] = *(const bf16x8*)&Bs[(wc * 64 + n * 16 + rl) * BK + kc];

    #pragma unroll
    for (int m = 0; m < 4; ++m)
      #pragma unroll
      for (int n = 0; n < 4; ++n)
        acc[m][n] = __builtin_amdgcn_mfma_f32_16x16x32_bf16(af[m], bfr[n], acc[m][n], 0, 0, 0);

    __syncthreads();
  }

  // Epilogue: C/D layout col = lane&15, row = (lane>>4)*4 + v  [guide §3, m89/m91]
  #pragma unroll
  for (int m = 0; m < 4; ++m) {
    int r0 = rowBase + wr * 64 + m * 16 + (lane >> 4) * 4;
    float4 xv = *(const float4*)&x2[r0];
    const float* xs = (const float*)&xv;
    #pragma unroll
    for (int n = 0; n < 4; ++n) {
      int c0 = colBase + wc * 64 + n * 16 + (lane & 15);
      float yv = y2[c0];
      float* op = out + (size_t)r0 * N_DIM + c0;
      #pragma unroll
      for (int v = 0; v < 4; ++v) {
        float d = xs[v] + yv - 2.0f * acc[m][n][v];
        op[(size_t)v * N_DIM] = fmaxf(d, 0.f);
      }
    }
  }
}

// Emergency fallback (ws too small): direct fp32, one thread per output.
__global__ __launch_bounds__(256) void fallback_kernel(
    const float* __restrict__ x, const float* __restrict__ y, float* __restrict__ out)
{
  size_t gid = (size_t)blockIdx.x * 256 + threadIdx.x;
  int i = (int)(gid >> 13);
  int j = (int)(gid & 8191);
  const float4* xr = (const float4*)(x + (size_t)i * D_DIM);
  const float4* yr = (const float4*)(y + (size_t)j * D_DIM);
  float acc = 0.f;
  for (int d = 0; d < D_DIM / 4; ++d) {
    float4 a = xr[d], b = yr[d];
    float dx = a.x - b.x, dy = a.y - b.y, dz = a.z - b.z, dw = a.w - b.w;
    acc += dx * dx + dy * dy + dz * dz + dw * dw;
  }
  out[gid] = fmaxf(acc, 0.f);
}

extern "C" void kernel_launch(void* const* d_in, const int* in_sizes, int n_in,
                              void* d_out, int out_size, void* d_ws, size_t ws_size,
                              hipStream_t stream)
{
  const float* x = (const float*)d_in[0];
  const float* y = (const float*)d_in[1];
  float* out = (float*)d_out;

  size_t packBytes = (size_t)M_DIM * K_DIM * sizeof(__hip_bfloat16); // 37,748,736 B
  size_t need = 2 * packBytes + 2 * (size_t)M_DIM * sizeof(float);
  if (ws_size < need) {
    fallback_kernel<<<((size_t)M_DIM * N_DIM) / 256, 256, 0, stream>>>(x, y, out);
    return;
  }

  __hip_bfloat16* Ap = (__hip_bfloat16*)d_ws;
  __hip_bfloat16* Bp = (__hip_bfloat16*)((char*)d_ws + packBytes);
  float* x2 = (float*)((char*)d_ws + 2 * packBytes);
  float* y2 = x2 + M_DIM;

  // x rows -> [hi, hi, lo]; y rows -> [hi, lo, hi]
  // dot = hi.hi + hi.lo + lo.hi  (lo.lo dropped, ~2^-16 relative)
  pack_kernel<<<M_DIM, 256, 0, stream>>>(x, Ap, x2, 0, D_DIM, 2 * D_DIM);
  pack_kernel<<<N_DIM, 256, 0, stream>>>(y, Bp, y2, 0, 2 * D_DIM, D_DIM);

  dist_gemm<<<(M_DIM / BM) * (N_DIM / BN), 256, 0, stream>>>(Ap, Bp, x2, y2, out);
}

// Round 5
// 680.591 us; speedup vs baseline: 1.0204x; 1.0204x over previous
//
#include <hip/hip_runtime.h>
#include <hip/hip_bf16.h>
#include <stdint.h>

// Pairwise squared L2: out[i][j] = max(x2[i] + y2[j] - 2*dot(x_i,y_j), 0)
// dot via bf16x3 split (hi/lo) single GEMM, K = 3*D = 2304.
// GEMM: 256x256 tile, BK=32, 8 waves, 4-deep LDS pipeline with counted vmcnt.

#define M_DIM 8192
#define N_DIM 8192
#define D_DIM 768
#define K_DIM (3 * D_DIM)   // 2304
#define BM 256
#define BN 256
#define BK 32
#define KT (K_DIM / BK)     // 72

typedef __bf16 bf16x8 __attribute__((ext_vector_type(8)));
typedef float f32x4 __attribute__((ext_vector_type(4)));

#define GLOAD_LDS16(g, l) \
  __builtin_amdgcn_global_load_lds((const __attribute__((address_space(1))) void*)(g), \
                                   (__attribute__((address_space(3))) void*)(l), 16, 0, 0)

// ---- pack: fp32 row -> bf16 [seg,seg,seg] (hi at off_hi0/off_hi1, lo at off_lo) + row ||.||^2
// One row per wave, 4 rows per block. Vectorized: float4 loads, uint4 (8xbf16) stores.
__global__ __launch_bounds__(256) void pack_kernel(
    const float* __restrict__ in, __hip_bfloat16* __restrict__ pk,
    float* __restrict__ nrm, int off_hi0, int off_hi1, int off_lo)
{
  int wid = threadIdx.x >> 6, lane = threadIdx.x & 63;
  int row = blockIdx.x * 4 + wid;
  const float* r = in + (size_t)row * D_DIM;
  __hip_bfloat16* p = pk + (size_t)row * K_DIM;
  float ss = 0.f;

  auto proc = [&](int u) {
    float4 a = *(const float4*)(r + u * 8);
    float4 b = *(const float4*)(r + u * 8 + 4);
    float v[8] = {a.x, a.y, a.z, a.w, b.x, b.y, b.z, b.w};
    union { __hip_bfloat16 h[8]; uint4 q; } H, L;
    #pragma unroll
    for (int j = 0; j < 8; ++j) {
      float x = v[j];
      ss += x * x;
      __hip_bfloat16 hi = __float2bfloat16(x);
      H.h[j] = hi;
      L.h[j] = __float2bfloat16(x - __bfloat162float(hi));
    }
    *(uint4*)(p + off_hi0 + u * 8) = H.q;
    *(uint4*)(p + off_hi1 + u * 8) = H.q;
    *(uint4*)(p + off_lo  + u * 8) = L.q;
  };

  proc(lane);                       // units 0..63
  if (lane < 32) proc(64 + lane);   // units 64..95  (96*8 = 768 = D)

  #pragma unroll
  for (int o = 1; o < 64; o <<= 1) ss += __shfl_xor(ss, o, 64);
  if (lane == 0) nrm[row] = ss;
}

// ---- GEMM with fused distance epilogue ----
__global__ __launch_bounds__(512, 2) void dist_gemm(
    const __hip_bfloat16* __restrict__ A, const __hip_bfloat16* __restrict__ Bp,
    const float* __restrict__ x2, const float* __restrict__ y2,
    float* __restrict__ out)
{
  // 4 buffers x (A 16KB + B 16KB) = 128 KiB
  __shared__ __attribute__((aligned(16))) __hip_bfloat16 As[4][BM * BK];
  __shared__ __attribute__((aligned(16))) __hip_bfloat16 Bs[4][BN * BK];

  int bid = blockIdx.x;
  // XCD-aware bijective swizzle: 1024 blocks, 1024 % 8 == 0
  int swz = (bid & 7) * 128 + (bid >> 3);
  int tileRow = swz >> 5;          // 32 tiles per dim
  int tileCol = swz & 31;
  int rowBase = tileRow * BM;
  int colBase = tileCol * BN;

  int tid  = threadIdx.x;
  int lane = tid & 63;
  int wid  = tid >> 6;             // 0..7
  int wr = wid >> 2, wc = wid & 3; // wave -> (2 x 4) sub-tiles of 128x64
  int rl = lane & 15, g = lane >> 4;

  // Stage tile t (A and B, 16KB each) into buffer t&3.
  // LDS dest is linear (wave-uniform base + lane*16, HW-required);
  // read-side XOR swizzle byte^=((row&3)<<4) is inverse-applied to the
  // GLOBAL source address (rule #21: both-sides-or-neither).
  auto STAGE = [&](int t) {
    int b = t & 3;
    int k0 = t * BK;
    #pragma unroll
    for (int s = 0; s < 2; ++s) {
      int pby = (s * 512 + tid) * 16;          // physical byte in 16KB tile
      int o = pby ^ ((pby >> 2) & 48);         // logical byte (involution)
      int row = o >> 6, colb = o & 63;
      const __hip_bfloat16* ga = A  + (size_t)(rowBase + row) * K_DIM + k0 + (colb >> 1);
      const __hip_bfloat16* gb = Bp + (size_t)(colBase + row) * K_DIM + k0 + (colb >> 1);
      GLOAD_LDS16(ga, (char*)&As[b][0] + s * 8192 + wid * 1024);
      GLOAD_LDS16(gb, (char*)&Bs[b][0] + s * 8192 + wid * 1024);
    }
  };

  f32x4 acc[8][4];
  #pragma unroll
  for (int m = 0; m < 8; ++m)
    #pragma unroll
    for (int n = 0; n < 4; ++n)
      acc[m][n] = (f32x4){0.f, 0.f, 0.f, 0.f};

  // Prologue: prefetch tiles 0..2; ensure tile 0 landed (vmcnt: 8 = tiles 1,2 in flight)
  STAGE(0); STAGE(1); STAGE(2);
  asm volatile("s_waitcnt vmcnt(8)" ::: "memory");
  __builtin_amdgcn_s_barrier();

  for (int kt = 0; kt < KT; ++kt) {
    int b = kt & 3;
    if (kt + 3 < KT) STAGE(kt + 3);  // dest buffer last read at kt-1, already barrier-retired

    bf16x8 af[8], bf[4];
    #pragma unroll
    for (int m = 0; m < 8; ++m) {
      int row = wr * 128 + m * 16 + rl;
      af[m] = *(const bf16x8*)((const char*)&As[b][0] + (row << 6) + ((g << 4) ^ ((row & 3) << 4)));
    }
    #pragma unroll
    for (int n = 0; n < 4; ++n) {
      int row = wc * 64 + n * 16 + rl;
      bf[n] = *(const bf16x8*)((const char*)&Bs[b][0] + (row << 6) + ((g << 4) ^ ((row & 3) << 4)));
    }

    __builtin_amdgcn_s_setprio(1);
    #pragma unroll
    for (int m = 0; m < 8; ++m)
      #pragma unroll
      for (int n = 0; n < 4; ++n)
        acc[m][n] = __builtin_amdgcn_mfma_f32_16x16x32_bf16(af[m], bf[n], acc[m][n], 0, 0, 0);
    __builtin_amdgcn_s_setprio(0);

    // Counted vmcnt: guarantee tile kt+1 landed; keep kt+2/kt+3 in flight.
    if (kt < KT - 3)       asm volatile("s_waitcnt vmcnt(8)" ::: "memory");
    else if (kt == KT - 3) asm volatile("s_waitcnt vmcnt(4)" ::: "memory");
    else if (kt == KT - 2) asm volatile("s_waitcnt vmcnt(0)" ::: "memory");
    if (kt < KT - 1) __builtin_amdgcn_s_barrier();
  }

  // Epilogue: C/D layout col = lane&15, row = (lane>>4)*4 + v
  #pragma unroll
  for (int m = 0; m < 8; ++m) {
    int r0 = rowBase + wr * 128 + m * 16 + (lane >> 4) * 4;
    float4 xv = *(const float4*)&x2[r0];
    const float* xs = (const float*)&xv;
    #pragma unroll
    for (int n = 0; n < 4; ++n) {
      int c0 = colBase + wc * 64 + n * 16 + (lane & 15);
      float yv = y2[c0];
      float* op = out + (size_t)r0 * N_DIM + c0;
      #pragma unroll
      for (int v = 0; v < 4; ++v) {
        float d = xs[v] + yv - 2.0f * acc[m][n][v];
        op[(size_t)v * N_DIM] = fmaxf(d, 0.f);
      }
    }
  }
}

// Emergency fallback (ws too small): direct fp32, one thread per output.
__global__ __launch_bounds__(256) void fallback_kernel(
    const float* __restrict__ x, const float* __restrict__ y, float* __restrict__ out)
{
  size_t gid = (size_t)blockIdx.x * 256 + threadIdx.x;
  int i = (int)(gid >> 13);
  int j = (int)(gid & 8191);
  const float4* xr = (const float4*)(x + (size_t)i * D_DIM);
  const float4* yr = (const float4*)(y + (size_t)j * D_DIM);
  float acc = 0.f;
  for (int d = 0; d < D_DIM / 4; ++d) {
    float4 a = xr[d], b = yr[d];
    float dx = a.x - b.x, dy = a.y - b.y, dz = a.z - b.z, dw = a.w - b.w;
    acc += dx * dx + dy * dy + dz * dz + dw * dw;
  }
  out[gid] = fmaxf(acc, 0.f);
}

extern "C" void kernel_launch(void* const* d_in, const int* in_sizes, int n_in,
                              void* d_out, int out_size, void* d_ws, size_t ws_size,
                              hipStream_t stream)
{
  const float* x = (const float*)d_in[0];
  const float* y = (const float*)d_in[1];
  float* out = (float*)d_out;

  size_t packBytes = (size_t)M_DIM * K_DIM * sizeof(__hip_bfloat16); // 37,748,736 B
  size_t need = 2 * packBytes + 2 * (size_t)M_DIM * sizeof(float);
  if (ws_size < need) {
    fallback_kernel<<<((size_t)M_DIM * N_DIM) / 256, 256, 0, stream>>>(x, y, out);
    return;
  }

  __hip_bfloat16* Ap = (__hip_bfloat16*)d_ws;
  __hip_bfloat16* Bp = (__hip_bfloat16*)((char*)d_ws + packBytes);
  float* x2 = (float*)((char*)d_ws + 2 * packBytes);
  float* y2 = x2 + M_DIM;

  // x rows -> [hi, hi, lo]; y rows -> [hi, lo, hi]
  // dot = hi.hi + hi.lo + lo.hi  (lo.lo dropped, ~2^-16 relative)
  pack_kernel<<<M_DIM / 4, 256, 0, stream>>>(x, Ap, x2, 0, D_DIM, 2 * D_DIM);
  pack_kernel<<<N_DIM / 4, 256, 0, stream>>>(y, Bp, y2, 0, 2 * D_DIM, D_DIM);

  dist_gemm<<<(M_DIM / BM) * (N_DIM / BN), 512, 0, stream>>>(Ap, Bp, x2, y2, out);
}

// Round 6
// 624.110 us; speedup vs baseline: 1.1127x; 1.0905x over previous
//
#include <hip/hip_runtime.h>
#include <hip/hip_bf16.h>
#include <stdint.h>

// Pairwise squared L2: out[i][j] = max(x2[i] + y2[j] - 2*dot(x_i,y_j), 0)
// dot via bf16x3 split single GEMM, K = 3*D = 2304.
// GEMM: 256x256 tile, BK=64, 8 waves, 4-phase-per-K-tile schedule (m201-style):
// per phase {ds_read frags || stage 1 quarter -> bar -> lgkm0 -> 16 MFMA -> bar},
// counted vmcnt(4)/vmcnt(2) only, T2 XOR-swizzle, T5 setprio.

#define M_DIM 8192
#define N_DIM 8192
#define D_DIM 768
#define K_DIM (3 * D_DIM)   // 2304
#define BM 256
#define BN 256
#define KSTEP 64
#define NT (K_DIM / KSTEP)  // 36

typedef __bf16 bf16x8 __attribute__((ext_vector_type(8)));
typedef float f32x4 __attribute__((ext_vector_type(4)));

#define GLOAD_LDS16(g, l) \
  __builtin_amdgcn_global_load_lds((const __attribute__((address_space(1))) void*)(g), \
                                   (__attribute__((address_space(3))) void*)(l), 16, 0, 0)

#define BAR()   __builtin_amdgcn_s_barrier()
#define LGKM0() do { asm volatile("s_waitcnt lgkmcnt(0)" ::: "memory"); \
                     __builtin_amdgcn_sched_barrier(0); } while (0)
#define VMCNT(N) do { asm volatile("s_waitcnt vmcnt(" #N ")" ::: "memory"); \
                      __builtin_amdgcn_sched_barrier(0); } while (0)

// ---- fused pack: rows [0,8192) from x -> Ap/x2, rows [8192,16384) from y -> Bp/y2.
// x rows -> [hi, hi, lo]; y rows -> [hi, lo, hi]  (dot = hi.hi + hi.lo + lo.hi)
__global__ __launch_bounds__(256) void pack2_kernel(
    const float* __restrict__ x, const float* __restrict__ y,
    __hip_bfloat16* __restrict__ Ap, __hip_bfloat16* __restrict__ Bp,
    float* __restrict__ x2, float* __restrict__ y2)
{
  int wid = threadIdx.x >> 6, lane = threadIdx.x & 63;
  int grow = blockIdx.x * 4 + wid;           // 0..16383
  bool isx = grow < M_DIM;
  int row = isx ? grow : grow - M_DIM;
  const float* r = (isx ? x : y) + (size_t)row * D_DIM;
  __hip_bfloat16* p = (isx ? Ap : Bp) + (size_t)row * K_DIM;
  float* nrm = isx ? x2 : y2;
  int off_hi1 = isx ? D_DIM : 2 * D_DIM;
  int off_lo  = isx ? 2 * D_DIM : D_DIM;
  float ss = 0.f;

  auto proc = [&](int u) {
    float4 a = *(const float4*)(r + u * 8);
    float4 b = *(const float4*)(r + u * 8 + 4);
    float v[8] = {a.x, a.y, a.z, a.w, b.x, b.y, b.z, b.w};
    union { __hip_bfloat16 h[8]; uint4 q; } H, L;
    #pragma unroll
    for (int j = 0; j < 8; ++j) {
      float t = v[j];
      ss += t * t;
      __hip_bfloat16 hi = __float2bfloat16(t);
      H.h[j] = hi;
      L.h[j] = __float2bfloat16(t - __bfloat162float(hi));
    }
    *(uint4*)(p + u * 8) = H.q;               // hi at seg 0 always
    *(uint4*)(p + off_hi1 + u * 8) = H.q;     // (y: this is seg2-hi)
    *(uint4*)(p + off_lo  + u * 8) = L.q;
  };

  proc(lane);
  if (lane < 32) proc(64 + lane);             // 96*8 = 768 = D

  #pragma unroll
  for (int o = 1; o < 64; o <<= 1) ss += __shfl_xor(ss, o, 64);
  if (lane == 0) nrm[row] = ss;
}

// ---- GEMM with fused distance epilogue ----
__global__ __launch_bounds__(512, 2) void dist_gemm(
    const __hip_bfloat16* __restrict__ A, const __hip_bfloat16* __restrict__ Bp,
    const float* __restrict__ x2, const float* __restrict__ y2,
    float* __restrict__ out)
{
  // A: [2 dbuf][256 rows][64 k] (128B rows, 32KB/buf). B: [2 dbuf][2 k-half][256 rows][32 k] (64B rows, 16KB each).
  __shared__ __attribute__((aligned(16))) __hip_bfloat16 As[2][BM * KSTEP];
  __shared__ __attribute__((aligned(16))) __hip_bfloat16 Bs[2][2][BN * 32];

  int bid = blockIdx.x;
  int swz = (bid & 7) * 128 + (bid >> 3);     // 1024 blocks, bijective (1024 % 8 == 0)
  int rowBase = (swz >> 5) * BM;
  int colBase = (swz & 31) * BN;

  int tid  = threadIdx.x;
  int lane = tid & 63;
  int wid  = tid >> 6;                        // 0..7
  int wr = wid >> 2, wc = wid & 3;            // 2 x 4 waves, 128x64 out each
  int rl = lane & 15, g = lane >> 4;

  // Fragment-read byte columns (lane-constant; row&7 == rl&7, (row>>1)&3 == (rl>>1)&3):
  int cA0 = (g * 16) ^ ((rl & 7) << 4);       // A kk=0; kk=1 is cA0 ^ 64 (bit6 untouched by mask)
  int cB  = (g * 16) ^ (((rl >> 1) & 3) << 4);

  // Staging thread-constants (both-sides involution, rule #21):
  // A quarter: pby = s*8192 + tid*16; row = s*64 + (tid>>3); colbyte = ((tid&7)*16) ^ (((tid>>3)&7)<<4)
  // B quarter: pby = s*8192 + tid*16; row = s*128 + (tid>>2); colbyte = ((tid&3)*16) ^ (((tid>>3)&3)<<4)
  int sArow = tid >> 3;
  int sAcol = (((tid & 7) * 16) ^ (((tid >> 3) & 7) << 4)) >> 1;   // elem 0..63
  int sBrow = tid >> 2;
  int sBcol = (((tid & 3) * 16) ^ (((tid >> 3) & 3) << 4)) >> 1;   // elem 0..31

  const __hip_bfloat16* gA = A  + (size_t)(rowBase + sArow) * K_DIM + sAcol;
  const __hip_bfloat16* gB = Bp + (size_t)(colBase + sBrow) * K_DIM + sBcol;

  // stage A half h (rows h*128..h*128+127) of tile with k-origin k0 into buf
  auto stageA = [&](int buf, int h, int k0) {
    #pragma unroll
    for (int s = 0; s < 2; ++s)
      GLOAD_LDS16(gA + ((size_t)(h * 128 + s * 64) * K_DIM) + k0,
                  (char*)&As[buf][0] + h * 16384 + s * 8192 + wid * 1024);
  };
  // stage B k-half h (k0+h*32 .. +31, all 256 rows) into buf
  auto stageB = [&](int buf, int h, int k0) {
    #pragma unroll
    for (int s = 0; s < 2; ++s)
      GLOAD_LDS16(gB + ((size_t)(s * 128) * K_DIM) + k0 + h * 32,
                  (char*)&Bs[buf][h][0] + s * 8192 + wid * 1024);
  };

  bf16x8 af[4], bf[4];
  auto ldsA = [&](int buf, int G, int cc) {
    #pragma unroll
    for (int i = 0; i < 4; ++i)
      af[i] = *(const bf16x8*)((const char*)&As[buf][0] +
               (wr * 128 + (G * 4 + i) * 16 + rl) * 128 + cc);
  };
  auto ldsB = [&](int buf, int kk) {
    #pragma unroll
    for (int n = 0; n < 4; ++n)
      bf[n] = *(const bf16x8*)((const char*)&Bs[buf][kk][0] +
               (wc * 64 + n * 16 + rl) * 64 + cB);
  };

  f32x4 acc[8][4];
  #pragma unroll
  for (int m = 0; m < 8; ++m)
    #pragma unroll
    for (int n = 0; n < 4; ++n)
      acc[m][n] = (f32x4){0.f, 0.f, 0.f, 0.f};

  auto mmac = [&](int G) {
    __builtin_amdgcn_s_setprio(1);
    #pragma unroll
    for (int i = 0; i < 4; ++i)
      #pragma unroll
      for (int n = 0; n < 4; ++n)
        acc[G * 4 + i][n] = __builtin_amdgcn_mfma_f32_16x16x32_bf16(af[i], bf[n], acc[G * 4 + i][n], 0, 0, 0);
    __builtin_amdgcn_s_setprio(0);
  };

  // Prologue: stage tile 0 in consumption order; leave Bk1 in flight.
  stageA(0, 0, 0); stageA(0, 1, 0); stageB(0, 0, 0); stageB(0, 1, 0);
  VMCNT(2);
  BAR();

  // Main tiles 0..NT-2: stage tile t+1. Waits: P1-end vmcnt(4), P3-end vmcnt(2).
  for (int t = 0; t < NT - 1; ++t) {
    int buf = t & 1, nbuf = buf ^ 1, k0n = (t + 1) * KSTEP;
    // P0
    ldsA(buf, 0, cA0); ldsB(buf, 0);
    stageA(nbuf, 0, k0n);
    BAR(); LGKM0(); mmac(0); BAR();
    // P1
    ldsA(buf, 1, cA0);
    stageA(nbuf, 1, k0n);
    BAR(); LGKM0(); mmac(1);
    VMCNT(4); BAR();
    // P2
    ldsA(buf, 0, cA0 ^ 64); ldsB(buf, 1);
    stageB(nbuf, 0, k0n);
    BAR(); LGKM0(); mmac(0); BAR();
    // P3
    ldsA(buf, 1, cA0 ^ 64);
    stageB(nbuf, 1, k0n);
    BAR(); LGKM0(); mmac(1);
    VMCNT(2); BAR();
  }
  // Peeled last tile (buf = (NT-1)&1 = 1): no staging; drain Bk1 at P1-end.
  {
    const int buf = (NT - 1) & 1;
    ldsA(buf, 0, cA0); ldsB(buf, 0);
    BAR(); LGKM0(); mmac(0); BAR();
    ldsA(buf, 1, cA0);
    BAR(); LGKM0(); mmac(1);
    VMCNT(0); BAR();
    ldsA(buf, 0, cA0 ^ 64); ldsB(buf, 1);
    BAR(); LGKM0(); mmac(0); BAR();
    ldsA(buf, 1, cA0 ^ 64);
    BAR(); LGKM0(); mmac(1);
  }

  // Epilogue: C/D layout col = lane&15, row = (lane>>4)*4 + v
  #pragma unroll
  for (int m = 0; m < 8; ++m) {
    int r0 = rowBase + wr * 128 + m * 16 + (lane >> 4) * 4;
    float4 xv = *(const float4*)&x2[r0];
    const float* xs = (const float*)&xv;
    #pragma unroll
    for (int n = 0; n < 4; ++n) {
      int c0 = colBase + wc * 64 + n * 16 + (lane & 15);
      float yv = y2[c0];
      float* op = out + (size_t)r0 * N_DIM + c0;
      #pragma unroll
      for (int v = 0; v < 4; ++v) {
        float d = xs[v] + yv - 2.0f * acc[m][n][v];
        op[(size_t)v * N_DIM] = fmaxf(d, 0.f);
      }
    }
  }
}

// Emergency fallback (ws too small): direct fp32, one thread per output.
__global__ __launch_bounds__(256) void fallback_kernel(
    const float* __restrict__ x, const float* __restrict__ y, float* __restrict__ out)
{
  size_t gid = (size_t)blockIdx.x * 256 + threadIdx.x;
  int i = (int)(gid >> 13);
  int j = (int)(gid & 8191);
  const float4* xr = (const float4*)(x + (size_t)i * D_DIM);
  const float4* yr = (const float4*)(y + (size_t)j * D_DIM);
  float acc = 0.f;
  for (int d = 0; d < D_DIM / 4; ++d) {
    float4 a = xr[d], b = yr[d];
    float dx = a.x - b.x, dy = a.y - b.y, dz = a.z - b.z, dw = a.w - b.w;
    acc += dx * dx + dy * dy + dz * dz + dw * dw;
  }
  out[gid] = fmaxf(acc, 0.f);
}

extern "C" void kernel_launch(void* const* d_in, const int* in_sizes, int n_in,
                              void* d_out, int out_size, void* d_ws, size_t ws_size,
                              hipStream_t stream)
{
  const float* x = (const float*)d_in[0];
  const float* y = (const float*)d_in[1];
  float* out = (float*)d_out;

  size_t packBytes = (size_t)M_DIM * K_DIM * sizeof(__hip_bfloat16); // 37,748,736 B
  size_t need = 2 * packBytes + 2 * (size_t)M_DIM * sizeof(float);
  if (ws_size < need) {
    fallback_kernel<<<((size_t)M_DIM * N_DIM) / 256, 256, 0, stream>>>(x, y, out);
    return;
  }

  __hip_bfloat16* Ap = (__hip_bfloat16*)d_ws;
  __hip_bfloat16* Bp = (__hip_bfloat16*)((char*)d_ws + packBytes);
  float* x2 = (float*)((char*)d_ws + 2 * packBytes);
  float* y2 = x2 + M_DIM;

  pack2_kernel<<<(M_DIM + N_DIM) / 4, 256, 0, stream>>>(x, y, Ap, Bp, x2, y2);
  dist_gemm<<<(M_DIM / BM) * (N_DIM / BN), 512, 0, stream>>>(Ap, Bp, x2, y2, out);
}